// Round 8
// baseline (793.264 us; speedup 1.0000x reference)
//
#include <hip/hip_runtime.h>
#include <math.h>

#define T 64
#define NN 16384
#define NE 262144
#define FIN 8
#define H1H 12
#define C1C 16
#define HID 192
#define CAP2 95      // max recorded in-edges of node 0 per t (Poisson(16); P(>=95) ~ 0)
#define SCAP 96      // max active nodes per t (CAP2 sources + node 0)
#define DEGCAP 127   // max recorded in-degree of an active node (Poisson(16))
#define LH 128
#define G4 512
#define NB 32
#define NL 32

#define DEV __device__ __forceinline__

DEV float wave_max(float v){
  #pragma unroll
  for (int m = 32; m; m >>= 1) v = fmaxf(v, __shfl_xor(v, m));
  return v;
}
DEV float wave_sum(float v){
  #pragma unroll
  for (int m = 32; m; m >>= 1) v += __shfl_xor(v, m);
  return v;
}
DEV float leaky(float x){ return x >= 0.f ? x : 0.2f * x; }
DEV float sigmoidf(float x){ return 1.f / (1.f + expf(-x)); }

// alpha = 0.8*a + 0.1*s + 0.1*v with s: rows {1,2,12,19,22}->0, {7,14}->1
//                                  v: rows {10,13}->0.5, {17}->0
// => rows {1,2,7,10,12,13,14,17,19,22}: 0.9a; {7,14}: +0.1; {10,13}: +0.05
DEV float apply_edit(float a, int eid){
  if (eid >= 32) return a;
  const unsigned m09 = (1u<<1)|(1u<<2)|(1u<<7)|(1u<<10)|(1u<<12)|(1u<<13)|(1u<<14)|(1u<<17)|(1u<<19)|(1u<<22);
  const unsigned mp1 = (1u<<7)|(1u<<14);
  const unsigned mp05 = (1u<<10)|(1u<<13);
  unsigned b = 1u << eid;
  float r = (m09 & b) ? 0.9f * a : a;
  if (mp1 & b) r += 0.1f;
  if (mp05 & b) r += 0.05f;
  return r;
}

// ---- K1: find edges with dst==0 per timestep ----
__global__ __launch_bounds__(256) void k_scan0(const int* __restrict__ ei,
                                               int* __restrict__ cnt2, int* __restrict__ list2){
  long long gid = (long long)blockIdx.x * blockDim.x + threadIdx.x;
  long long e4 = gid * 4;
  int t = (int)(e4 >> 18);
  int e = (int)(e4 & (NE - 1));
  const int* dstp = ei + (size_t)t * 2 * NE + NE + e;
  int4 d = *(const int4*)dstp;
  int dd[4] = {d.x, d.y, d.z, d.w};
  #pragma unroll
  for (int q = 0; q < 4; q++){
    if (dd[q] == 0){
      int pos = atomicAdd(&cnt2[t], 1);
      if (pos < CAP2) list2[t * CAP2 + pos] = e + q;
    }
  }
}

// ---- K2: build active node set S = {sources of dst-0 edges} ∪ {0}, with slot map ----
// slot value is never read within this kernel (CAS losers skip) -> relaxed store, no wbl2.
__global__ __launch_bounds__(128) void k_build(const int* __restrict__ ei, const int* __restrict__ cnt2,
                                               const int* __restrict__ list2, int* __restrict__ scnt,
                                               int* __restrict__ Slist, int* __restrict__ slot_of){
  int t = blockIdx.x;
  int* so = slot_of + (size_t)t * NN;
  int m = min(cnt2[t], CAP2);
  for (int i = threadIdx.x; i < m + 1; i += blockDim.x){
    int u = (i == m) ? 0 : ei[(size_t)t * 2 * NE + list2[t * CAP2 + i]];
    int old = atomicCAS(&so[u], -1, -2);
    if (old == -1){
      int s = atomicAdd(&scnt[t], 1);
      Slist[t * SCAP + s] = u;
      __hip_atomic_store(&so[u], s, __ATOMIC_RELAXED, __HIP_MEMORY_SCOPE_AGENT);
    }
  }
}

// ---- K3: collect in-edges of every node in S ----
__global__ __launch_bounds__(256) void k_scan1(const int* __restrict__ ei, const int* __restrict__ slot_of,
                                               int* __restrict__ ecnt1, int* __restrict__ elist1){
  long long gid = (long long)blockIdx.x * blockDim.x + threadIdx.x;
  long long e4 = gid * 4;
  int t = (int)(e4 >> 18);
  int e = (int)(e4 & (NE - 1));
  const int* dstp = ei + (size_t)t * 2 * NE + NE + e;
  int4 d = *(const int4*)dstp;
  int dd[4] = {d.x, d.y, d.z, d.w};
  #pragma unroll
  for (int q = 0; q < 4; q++){
    int sl = slot_of[(size_t)t * NN + dd[q]];
    if (sl >= 0){
      int pos = atomicAdd(&ecnt1[t * SCAP + sl], 1);
      if (pos < DEGCAP) elist1[((size_t)t * SCAP + sl) * DEGCAP + pos] = e + q;
    }
  }
}

// ---- K4: layer-1 GAT at active nodes. One wave per (t, slot, head). ----
// Round-4 post-mortem: one wave per (t,slot) doing all 12 heads serially = ~1100 waves on 1024
// SIMDs -> 1 wave/SIMD, pure latency-bound on swizzle-reduction chains (VALUBusy 12%). Head dim
// is parallel after the gather: grid z = head -> 12x waves, 12x less per-wave latency.
// __launch_bounds__(64,4): 128-VGPR cap so xls arrays + 16 reduction chains stay in regs (r4's
// 64-VGPR alloc serialized them), 4 waves/SIMD co-residency for latency hiding.
__global__ __launch_bounds__(64, 4) void k_gat1(const float* __restrict__ x, const int* __restrict__ ei,
                                             const float* __restrict__ Wl1, const float* __restrict__ attl,
                                             const float* __restrict__ attr, const float* __restrict__ b1,
                                             const int* __restrict__ scnt, const int* __restrict__ Slist,
                                             const int* __restrict__ ecnt1, const int* __restrict__ elist1,
                                             float* __restrict__ h1){
  int t = blockIdx.y, s = blockIdx.x, h = blockIdx.z;
  if (s >= scnt[t]) return;
  int lane = threadIdx.x;
  int u = Slist[t * SCAP + s];
  int deg = min(ecnt1[t * SCAP + s], DEGCAP);
  int tot = deg + 1;                      // + self loop (appended after edges; id >= NE, never special)
  bool two = tot > 64;                    // wave-uniform: second chunk needed (rare: deg ~ Poisson(16))
  const float* xt = x + (size_t)t * NN * FIN;
  const int* srcp = ei + (size_t)t * 2 * NE;
  const int* el = elist1 + ((size_t)t * SCAP + s) * DEGCAP;

  float4 xu_a = ((const float4*)(xt + (size_t)u * FIN))[0];
  float4 xu_b = ((const float4*)(xt + (size_t)u * FIN))[1];
  float xu[FIN] = {xu_a.x, xu_a.y, xu_a.z, xu_a.w, xu_b.x, xu_b.y, xu_b.z, xu_b.w};

  // chunk 0 (lanes 0..63)
  bool act0 = lane < tot;
  int eid0 = 1 << 29;
  int su0 = u;
  if (lane < deg){ int e = el[lane]; eid0 = e; su0 = srcp[e]; }
  float4 xs0a = ((const float4*)(xt + (size_t)su0 * FIN))[0];
  float4 xs0b = ((const float4*)(xt + (size_t)su0 * FIN))[1];
  float xsrc0[FIN] = {xs0a.x, xs0a.y, xs0a.z, xs0a.w, xs0b.x, xs0b.y, xs0b.z, xs0b.w};

  // chunk 1 (lanes 64..127) — only if deg+1 > 64
  bool act1 = false; int eid1 = 1 << 29;
  float xsrc1[FIN];
  if (two){
    int idx = 64 + lane;
    act1 = idx < tot;
    int su1 = u;
    if (idx < deg){ int e = el[idx]; eid1 = e; su1 = srcp[e]; }
    float4 xs1a = ((const float4*)(xt + (size_t)su1 * FIN))[0];
    float4 xs1b = ((const float4*)(xt + (size_t)su1 * FIN))[1];
    #pragma unroll
    for (int f = 0; f < 4; f++) xsrc1[f] = (&xs1a.x)[f];
    #pragma unroll
    for (int f = 0; f < 4; f++) xsrc1[4 + f] = (&xs1b.x)[f];
  }

  const float* Wh = Wl1 + h * C1C;        // column block of head h: Wh[f*HID + c]
  const float* attlh = attl + h * C1C;
  const float* attrh = attr + h * C1C;

  // ar (same for all lanes): dst-node projection dotted with att_r — no xlu array kept
  float ar = 0.f;
  #pragma unroll
  for (int c = 0; c < C1C; c++){
    float v = 0.f;
    #pragma unroll
    for (int f = 0; f < FIN; f++) v = fmaf(xu[f], Wh[f * HID + c], v);
    ar = fmaf(v, attrh[c], ar);
  }

  float xls0[C1C];
  float al0 = 0.f;
  #pragma unroll
  for (int c = 0; c < C1C; c++){
    float v = 0.f;
    #pragma unroll
    for (int f = 0; f < FIN; f++) v = fmaf(xsrc0[f], Wh[f * HID + c], v);
    xls0[c] = v;
    al0 = fmaf(v, attlh[c], al0);
  }
  float raw0 = act0 ? leaky(al0 + ar) : -INFINITY;

  float xls1[C1C];
  float raw1 = -INFINITY;
  if (two){
    float al1 = 0.f;
    #pragma unroll
    for (int c = 0; c < C1C; c++){
      float v = 0.f;
      #pragma unroll
      for (int f = 0; f < FIN; f++) v = fmaf(xsrc1[f], Wh[f * HID + c], v);
      xls1[c] = v;
      al1 = fmaf(v, attlh[c], al1);
    }
    raw1 = act1 ? leaky(al1 + ar) : -INFINITY;
  }

  float M = wave_max(fmaxf(raw0, raw1));
  float ex0 = act0 ? expf(raw0 - M) : 0.f;
  float ex1 = act1 ? expf(raw1 - M) : 0.f;
  float S = wave_sum(ex0 + ex1);
  float den = S + 1e-16f;
  float alpha0 = apply_edit(ex0 / den, eid0);
  float alpha1 = two ? apply_edit(ex1 / den, eid1) : 0.f;

  // 16 independent reductions, batched level-by-level so the chains pipeline
  float sum[C1C];
  #pragma unroll
  for (int c = 0; c < C1C; c++){
    sum[c] = xls0[c] * alpha0;
    if (two) sum[c] = fmaf(xls1[c], alpha1, sum[c]);
  }
  #pragma unroll
  for (int m = 32; m; m >>= 1){
    #pragma unroll
    for (int c = 0; c < C1C; c++) sum[c] += __shfl_xor(sum[c], m);
  }
  if (lane == 0){
    float* h1p = h1 + ((size_t)t * SCAP + s) * HID + h * C1C;
    #pragma unroll
    for (int c = 0; c < C1C; c++){
      float v = sum[c] + b1[h * C1C + c];
      h1p[c] = v > 0.f ? v : expm1f(v);   // ELU
    }
  }
}

// ---- K5: layer-2 GAT at node 0 only -> series[t]. One wave per t. ----
__global__ __launch_bounds__(64) void k_gat2(const int* __restrict__ ei, const float* __restrict__ Wl2,
                                             const float* __restrict__ attl2_, const float* __restrict__ attr2_,
                                             const float* __restrict__ b2, const int* __restrict__ cnt2,
                                             const int* __restrict__ list2, const int* __restrict__ slot_of,
                                             const float* __restrict__ h1, float* __restrict__ series){
  int t = blockIdx.x; int lane = threadIdx.x;
  int deg = min(cnt2[t], CAP2);
  int tot = deg + 1;
  const int* srcp = ei + (size_t)t * 2 * NE;
  const int* so = slot_of + (size_t)t * NN;
  float attl2 = attl2_[0], attr2 = attr2_[0];
  int sl0 = so[0];
  const float* h1t = h1 + (size_t)t * SCAP * HID;

  float x0 = 0.f;
  for (int k = 0; k < HID; k++) x0 += h1t[(size_t)sl0 * HID + k] * Wl2[k];

  bool act[2]; int eid[2]; float xl2[2];
  #pragma unroll
  for (int ch = 0; ch < 2; ch++){
    int idx = ch * 64 + lane;
    act[ch] = idx < tot;
    eid[ch] = 1 << 29;
    int sl = sl0;
    if (idx < deg){ int e = list2[t * CAP2 + idx]; eid[ch] = e; sl = so[srcp[e]]; }
    float v = 0.f;
    if (act[ch]) for (int k = 0; k < HID; k++) v += h1t[(size_t)sl * HID + k] * Wl2[k];
    xl2[ch] = v;
  }
  float raw[2];
  #pragma unroll
  for (int ch = 0; ch < 2; ch++) raw[ch] = act[ch] ? leaky(attl2 * xl2[ch] + attr2 * x0) : -INFINITY;
  float M = wave_max(fmaxf(raw[0], raw[1]));
  float ex[2];
  #pragma unroll
  for (int ch = 0; ch < 2; ch++) ex[ch] = act[ch] ? expf(raw[ch] - M) : 0.f;
  float S = wave_sum(ex[0] + ex[1]);
  float den = S + 1e-16f;
  float contrib = apply_edit(ex[0] / den, eid[0]) * xl2[0] + apply_edit(ex[1] / den, eid[1]) * xl2[1];
  contrib = wave_sum(contrib);
  if (lane == 0) series[t] = contrib + b2[0];   // 1 head, mean == identity
}

// ---- K7: LSTM — 1024 thr/block, pair-per-row, interleaved halves, streaming loads. ----
// Round-12 post-mortem: r7 matched prediction (94us, conflicts 0, VGPR 52) — L2-weight-stream
// bound per CU, ~1us/step for 96 iterations (64 recurrence + 32 phase-B sweeps). Phases A/C are
// true recurrences (must re-stream: h changes each step). Phase B is NOT: it re-read all of Wih1
// once per t (32 x 256KB = 8MB/block) for independent matvecs.
// This round: phase B retiled — hold each weight float4 in a register, apply to 8 timesteps
// (8 float4 accumulators, statically indexed -> ~55 VGPR < 128 cap). Weight traffic in B drops
// 8x; LDS reads, FMA count, and per-dot accumulation order (i sequential per t) unchanged.
// Verify: dur ~68-75us, WRITE_SIZE stays ~0 (a jump = acc tile spilled -> drop to 4 timesteps).
#define B8(M) M(0)M(1)M(2)M(3)M(4)M(5)M(6)M(7)
#define ADECL(k) float4 c##k = {0.f, 0.f, 0.f, 0.f};
#define AHP(k)   const float4* hp##k = (const float4*)h0buf[t0 + k];
#define AFMA(k)  { float4 hv = hp##k[2 * i + hf]; \
                   c##k.x = fmaf(w.x, hv.x, c##k.x); c##k.y = fmaf(w.y, hv.y, c##k.y); \
                   c##k.z = fmaf(w.z, hv.z, c##k.z); c##k.w = fmaf(w.w, hv.w, c##k.w); }
#define AOUT(k)  { float half = (c##k.x + c##k.y) + (c##k.z + c##k.w); \
                   float full = half + __shfl_xor(half, 1); \
                   if (!hf) xp_lds[(t0 + k) * G4 + r] = full; }

__global__ __launch_bounds__(1024, 4) void k_lstm(const float* __restrict__ series,
    const float* __restrict__ Wih0, const float* __restrict__ Whh0,
    const float* __restrict__ bih0, const float* __restrict__ bhh0,
    const float* __restrict__ Wih1, const float* __restrict__ Whh1,
    const float* __restrict__ bih1, const float* __restrict__ bhh1,
    const float* __restrict__ Wlin, const float* __restrict__ blin,
    float* __restrict__ out){
  int tid = threadIdx.x;
  int b = blockIdx.x;
  int r  = tid >> 1;        // gate row 0..511
  int hf = tid & 1;         // which interleaved half of the 128-dot this thread owns
  int cls = r >> 7;         // gate class 0:i 1:f 2:g 3:o — g uses tanh, rest sigmoid
  __shared__ __align__(16) float h_lds[LH];
  __shared__ __align__(16) float c_lds[LH];
  __shared__ __align__(16) float gate_lds[G4];
  __shared__ __align__(16) float s_series[NL];
  __shared__ __align__(16) float h0buf[NL][LH];     // 16 KB: layer-0 hidden states
  __shared__ __align__(16) float xp_lds[NL * G4];   // 64 KB: Wih1 @ h0 for all t

  // ---------- phase A: layer-0 recurrence ----------
  {
    const float4* Wr = (const float4*)(Whh0 + (size_t)r * LH);
    const float4* hp = (const float4*)h_lds;
    float wih = Wih0[r];
    float bsum = bih0[r] + bhh0[r];
    if (tid < LH){ h_lds[tid] = 0.f; c_lds[tid] = 0.f; }
    if (tid < NL) s_series[tid] = series[b + tid];
    __syncthreads();
    for (int t = 0; t < NL; t++){
      float a0 = 0.f, a1 = 0.f, a2 = 0.f, a3 = 0.f;
      #pragma unroll
      for (int i = 0; i < 16; i++){
        float4 w = Wr[2 * i + hf];
        float4 hv = hp[2 * i + hf];
        a0 = fmaf(w.x, hv.x, a0); a1 = fmaf(w.y, hv.y, a1);
        a2 = fmaf(w.z, hv.z, a2); a3 = fmaf(w.w, hv.w, a3);
      }
      float half = (a0 + a1) + (a2 + a3);
      float full = half + __shfl_xor(half, 1);
      if (!hf){
        float acc = fmaf(wih, s_series[t], bsum) + full;
        gate_lds[r] = (cls == 2) ? tanhf(acc) : sigmoidf(acc);
      }
      __syncthreads();
      if (tid < LH){
        float c = gate_lds[LH + tid] * c_lds[tid] + gate_lds[tid] * gate_lds[2 * LH + tid];
        float h = gate_lds[3 * LH + tid] * tanhf(c);
        c_lds[tid] = c; h_lds[tid] = h; h0buf[t][tid] = h;
      }
      __syncthreads();
    }
  }

  // ---------- phase B: xp[t][r] = Wih1[r,:] @ h0[t] — weight-register tiling over 8 t's ----------
  {
    const float4* Wr = (const float4*)(Wih1 + (size_t)r * LH);
    for (int t0 = 0; t0 < NL; t0 += 8){
      B8(AHP)
      B8(ADECL)
      #pragma unroll
      for (int i = 0; i < 16; i++){
        float4 w = Wr[2 * i + hf];
        B8(AFMA)
      }
      B8(AOUT)
    }
  }

  // ---------- phase C: layer-1 recurrence ----------
  {
    const float4* Wr = (const float4*)(Whh1 + (size_t)r * LH);
    const float4* hp = (const float4*)h_lds;
    float bsum = bih1[r] + bhh1[r];
    __syncthreads();                      // all waves out of phase B before h/c reinit
    if (tid < LH){ h_lds[tid] = 0.f; c_lds[tid] = 0.f; }
    __syncthreads();
    for (int t = 0; t < NL; t++){
      float a0 = 0.f, a1 = 0.f, a2 = 0.f, a3 = 0.f;
      #pragma unroll
      for (int i = 0; i < 16; i++){
        float4 w = Wr[2 * i + hf];
        float4 hv = hp[2 * i + hf];
        a0 = fmaf(w.x, hv.x, a0); a1 = fmaf(w.y, hv.y, a1);
        a2 = fmaf(w.z, hv.z, a2); a3 = fmaf(w.w, hv.w, a3);
      }
      float half = (a0 + a1) + (a2 + a3);
      float full = half + __shfl_xor(half, 1);
      if (!hf){
        float acc = xp_lds[t * G4 + r] + bsum + full;   // xp: own pair's phase-B write
        gate_lds[r] = (cls == 2) ? tanhf(acc) : sigmoidf(acc);
      }
      __syncthreads();
      if (tid < LH){
        float c = gate_lds[LH + tid] * c_lds[tid] + gate_lds[tid] * gate_lds[2 * LH + tid];
        float h = gate_lds[3 * LH + tid] * tanhf(c);
        c_lds[tid] = c; h_lds[tid] = h;
      }
      __syncthreads();
    }
    if (tid == 0){
      float s2 = blin[0];
      for (int k = 0; k < LH; k++) s2 += Wlin[k] * h_lds[k];
      out[b] = s2;
    }
  }
}

extern "C" void kernel_launch(void* const* d_in, const int* in_sizes, int n_in,
                              void* d_out, int out_size, void* d_ws, size_t ws_size,
                              hipStream_t stream) {
  const float* x     = (const float*)d_in[0];
  const int*   ei    = (const int*)  d_in[1];
  const float* Wl1   = (const float*)d_in[2];
  const float* attl1 = (const float*)d_in[3];
  const float* attr1 = (const float*)d_in[4];
  const float* b1    = (const float*)d_in[5];
  const float* Wl2   = (const float*)d_in[6];
  const float* attl2 = (const float*)d_in[7];
  const float* attr2 = (const float*)d_in[8];
  const float* b2    = (const float*)d_in[9];
  const float* Wih0  = (const float*)d_in[10];
  const float* Whh0  = (const float*)d_in[11];
  const float* bih0  = (const float*)d_in[12];
  const float* bhh0  = (const float*)d_in[13];
  const float* Wih1  = (const float*)d_in[14];
  const float* Whh1  = (const float*)d_in[15];
  const float* bih1  = (const float*)d_in[16];
  const float* bhh1  = (const float*)d_in[17];
  const float* Wlin  = (const float*)d_in[18];
  const float* blin  = (const float*)d_in[19];
  float* out = (float*)d_out;

  char* wsb = (char*)d_ws;
  size_t off = 0;
  auto alloc = [&](size_t bytes)->void*{
    void* p = wsb + off;
    off += (bytes + 255) & ~(size_t)255;
    return p;
  };
  // control region (must be zeroed each launch — ws is poisoned 0xAA)
  int* cnt2  = (int*)alloc(T * 4);
  int* scnt  = (int*)alloc(T * 4);
  int* ecnt1 = (int*)alloc(T * SCAP * 4);
  size_t ctrl_bytes = off;
  int* slot_of = (int*)alloc((size_t)T * NN * 4);       // memset 0xFF -> -1
  int* list2   = (int*)alloc((size_t)T * CAP2 * 4);
  int* Slist   = (int*)alloc((size_t)T * SCAP * 4);
  int* elist1  = (int*)alloc((size_t)T * SCAP * DEGCAP * 4);
  float* h1    = (float*)alloc((size_t)T * SCAP * HID * 4);
  float* series= (float*)alloc(T * 4);

  hipMemsetAsync(d_ws, 0, ctrl_bytes, stream);
  hipMemsetAsync(slot_of, 0xFF, (size_t)T * NN * 4, stream);

  k_scan0<<<T * NE / 4 / 256, 256, 0, stream>>>(ei, cnt2, list2);
  k_build<<<T, 128, 0, stream>>>(ei, cnt2, list2, scnt, Slist, slot_of);
  k_scan1<<<T * NE / 4 / 256, 256, 0, stream>>>(ei, slot_of, ecnt1, elist1);
  k_gat1<<<dim3(SCAP, T, H1H), 64, 0, stream>>>(x, ei, Wl1, attl1, attr1, b1, scnt, Slist, ecnt1, elist1, h1);
  k_gat2<<<T, 64, 0, stream>>>(ei, Wl2, attl2, attr2, b2, cnt2, list2, slot_of, h1, series);
  k_lstm<<<NB, 1024, 0, stream>>>(series, Wih0, Whh0, bih0, bhh0, Wih1, Whh1, bih1, bhh1,
                                  Wlin, blin, out);
}

// Round 10
// 427.240 us; speedup vs baseline: 1.8567x; 1.8567x over previous
//
#include <hip/hip_runtime.h>
#include <math.h>

#define T 64
#define NN 16384
#define NE 262144
#define FIN 8
#define H1H 12
#define C1C 16
#define HID 192
#define CAP2 95      // max recorded in-edges of node 0 per t (Poisson(16); P(>=95) ~ 0)
#define SCAP 96      // max active nodes per t (CAP2 sources + node 0)
#define DEGCAP 127   // max recorded in-degree of an active node (Poisson(16))
#define LH 128
#define G4 512
#define NB 32
#define NL 32

#define DEV __device__ __forceinline__

DEV float wave_max(float v){
  #pragma unroll
  for (int m = 32; m; m >>= 1) v = fmaxf(v, __shfl_xor(v, m));
  return v;
}
DEV float wave_sum(float v){
  #pragma unroll
  for (int m = 32; m; m >>= 1) v += __shfl_xor(v, m);
  return v;
}
DEV float leaky(float x){ return x >= 0.f ? x : 0.2f * x; }
DEV float sigmoidf(float x){ return 1.f / (1.f + expf(-x)); }

// alpha = 0.8*a + 0.1*s + 0.1*v with s: rows {1,2,12,19,22}->0, {7,14}->1
//                                  v: rows {10,13}->0.5, {17}->0
// => rows {1,2,7,10,12,13,14,17,19,22}: 0.9a; {7,14}: +0.1; {10,13}: +0.05
DEV float apply_edit(float a, int eid){
  if (eid >= 32) return a;
  const unsigned m09 = (1u<<1)|(1u<<2)|(1u<<7)|(1u<<10)|(1u<<12)|(1u<<13)|(1u<<14)|(1u<<17)|(1u<<19)|(1u<<22);
  const unsigned mp1 = (1u<<7)|(1u<<14);
  const unsigned mp05 = (1u<<10)|(1u<<13);
  unsigned b = 1u << eid;
  float r = (m09 & b) ? 0.9f * a : a;
  if (mp1 & b) r += 0.1f;
  if (mp05 & b) r += 0.05f;
  return r;
}

// ---- K1: find edges with dst==0 per timestep ----
__global__ __launch_bounds__(256) void k_scan0(const int* __restrict__ ei,
                                               int* __restrict__ cnt2, int* __restrict__ list2){
  long long gid = (long long)blockIdx.x * blockDim.x + threadIdx.x;
  long long e4 = gid * 4;
  int t = (int)(e4 >> 18);
  int e = (int)(e4 & (NE - 1));
  const int* dstp = ei + (size_t)t * 2 * NE + NE + e;
  int4 d = *(const int4*)dstp;
  int dd[4] = {d.x, d.y, d.z, d.w};
  #pragma unroll
  for (int q = 0; q < 4; q++){
    if (dd[q] == 0){
      int pos = atomicAdd(&cnt2[t], 1);
      if (pos < CAP2) list2[t * CAP2 + pos] = e + q;
    }
  }
}

// ---- K2: build active node set S = {sources of dst-0 edges} ∪ {0}, with slot map ----
// slot value is never read within this kernel (CAS losers skip) -> relaxed store, no wbl2.
__global__ __launch_bounds__(128) void k_build(const int* __restrict__ ei, const int* __restrict__ cnt2,
                                               const int* __restrict__ list2, int* __restrict__ scnt,
                                               int* __restrict__ Slist, int* __restrict__ slot_of){
  int t = blockIdx.x;
  int* so = slot_of + (size_t)t * NN;
  int m = min(cnt2[t], CAP2);
  for (int i = threadIdx.x; i < m + 1; i += blockDim.x){
    int u = (i == m) ? 0 : ei[(size_t)t * 2 * NE + list2[t * CAP2 + i]];
    int old = atomicCAS(&so[u], -1, -2);
    if (old == -1){
      int s = atomicAdd(&scnt[t], 1);
      Slist[t * SCAP + s] = u;
      __hip_atomic_store(&so[u], s, __ATOMIC_RELAXED, __HIP_MEMORY_SCOPE_AGENT);
    }
  }
}

// ---- K3: collect in-edges of every node in S ----
__global__ __launch_bounds__(256) void k_scan1(const int* __restrict__ ei, const int* __restrict__ slot_of,
                                               int* __restrict__ ecnt1, int* __restrict__ elist1){
  long long gid = (long long)blockIdx.x * blockDim.x + threadIdx.x;
  long long e4 = gid * 4;
  int t = (int)(e4 >> 18);
  int e = (int)(e4 & (NE - 1));
  const int* dstp = ei + (size_t)t * 2 * NE + NE + e;
  int4 d = *(const int4*)dstp;
  int dd[4] = {d.x, d.y, d.z, d.w};
  #pragma unroll
  for (int q = 0; q < 4; q++){
    int sl = slot_of[(size_t)t * NN + dd[q]];
    if (sl >= 0){
      int pos = atomicAdd(&ecnt1[t * SCAP + sl], 1);
      if (pos < DEGCAP) elist1[((size_t)t * SCAP + sl) * DEGCAP + pos] = e + q;
    }
  }
}

// ---- K4: layer-1 GAT at active nodes. One wave per (t, slot, head). ----
// Round-4 post-mortem: one wave per (t,slot) doing all 12 heads serially = ~1100 waves on 1024
// SIMDs -> 1 wave/SIMD, pure latency-bound on swizzle-reduction chains (VALUBusy 12%). Head dim
// is parallel after the gather: grid z = head -> 12x waves, 12x less per-wave latency.
// __launch_bounds__(64,4): 128-VGPR cap so xls arrays + 16 reduction chains stay in regs (r4's
// 64-VGPR alloc serialized them), 4 waves/SIMD co-residency for latency hiding.
__global__ __launch_bounds__(64, 4) void k_gat1(const float* __restrict__ x, const int* __restrict__ ei,
                                             const float* __restrict__ Wl1, const float* __restrict__ attl,
                                             const float* __restrict__ attr, const float* __restrict__ b1,
                                             const int* __restrict__ scnt, const int* __restrict__ Slist,
                                             const int* __restrict__ ecnt1, const int* __restrict__ elist1,
                                             float* __restrict__ h1){
  int t = blockIdx.y, s = blockIdx.x, h = blockIdx.z;
  if (s >= scnt[t]) return;
  int lane = threadIdx.x;
  int u = Slist[t * SCAP + s];
  int deg = min(ecnt1[t * SCAP + s], DEGCAP);
  int tot = deg + 1;                      // + self loop (appended after edges; id >= NE, never special)
  bool two = tot > 64;                    // wave-uniform: second chunk needed (rare: deg ~ Poisson(16))
  const float* xt = x + (size_t)t * NN * FIN;
  const int* srcp = ei + (size_t)t * 2 * NE;
  const int* el = elist1 + ((size_t)t * SCAP + s) * DEGCAP;

  float4 xu_a = ((const float4*)(xt + (size_t)u * FIN))[0];
  float4 xu_b = ((const float4*)(xt + (size_t)u * FIN))[1];
  float xu[FIN] = {xu_a.x, xu_a.y, xu_a.z, xu_a.w, xu_b.x, xu_b.y, xu_b.z, xu_b.w};

  // chunk 0 (lanes 0..63)
  bool act0 = lane < tot;
  int eid0 = 1 << 29;
  int su0 = u;
  if (lane < deg){ int e = el[lane]; eid0 = e; su0 = srcp[e]; }
  float4 xs0a = ((const float4*)(xt + (size_t)su0 * FIN))[0];
  float4 xs0b = ((const float4*)(xt + (size_t)su0 * FIN))[1];
  float xsrc0[FIN] = {xs0a.x, xs0a.y, xs0a.z, xs0a.w, xs0b.x, xs0b.y, xs0b.z, xs0b.w};

  // chunk 1 (lanes 64..127) — only if deg+1 > 64
  bool act1 = false; int eid1 = 1 << 29;
  float xsrc1[FIN];
  if (two){
    int idx = 64 + lane;
    act1 = idx < tot;
    int su1 = u;
    if (idx < deg){ int e = el[idx]; eid1 = e; su1 = srcp[e]; }
    float4 xs1a = ((const float4*)(xt + (size_t)su1 * FIN))[0];
    float4 xs1b = ((const float4*)(xt + (size_t)su1 * FIN))[1];
    #pragma unroll
    for (int f = 0; f < 4; f++) xsrc1[f] = (&xs1a.x)[f];
    #pragma unroll
    for (int f = 0; f < 4; f++) xsrc1[4 + f] = (&xs1b.x)[f];
  }

  const float* Wh = Wl1 + h * C1C;        // column block of head h: Wh[f*HID + c]
  const float* attlh = attl + h * C1C;
  const float* attrh = attr + h * C1C;

  // ar (same for all lanes): dst-node projection dotted with att_r — no xlu array kept
  float ar = 0.f;
  #pragma unroll
  for (int c = 0; c < C1C; c++){
    float v = 0.f;
    #pragma unroll
    for (int f = 0; f < FIN; f++) v = fmaf(xu[f], Wh[f * HID + c], v);
    ar = fmaf(v, attrh[c], ar);
  }

  float xls0[C1C];
  float al0 = 0.f;
  #pragma unroll
  for (int c = 0; c < C1C; c++){
    float v = 0.f;
    #pragma unroll
    for (int f = 0; f < FIN; f++) v = fmaf(xsrc0[f], Wh[f * HID + c], v);
    xls0[c] = v;
    al0 = fmaf(v, attlh[c], al0);
  }
  float raw0 = act0 ? leaky(al0 + ar) : -INFINITY;

  float xls1[C1C];
  float raw1 = -INFINITY;
  if (two){
    float al1 = 0.f;
    #pragma unroll
    for (int c = 0; c < C1C; c++){
      float v = 0.f;
      #pragma unroll
      for (int f = 0; f < FIN; f++) v = fmaf(xsrc1[f], Wh[f * HID + c], v);
      xls1[c] = v;
      al1 = fmaf(v, attlh[c], al1);
    }
    raw1 = act1 ? leaky(al1 + ar) : -INFINITY;
  }

  float M = wave_max(fmaxf(raw0, raw1));
  float ex0 = act0 ? expf(raw0 - M) : 0.f;
  float ex1 = act1 ? expf(raw1 - M) : 0.f;
  float S = wave_sum(ex0 + ex1);
  float den = S + 1e-16f;
  float alpha0 = apply_edit(ex0 / den, eid0);
  float alpha1 = two ? apply_edit(ex1 / den, eid1) : 0.f;

  // 16 independent reductions, batched level-by-level so the chains pipeline
  float sum[C1C];
  #pragma unroll
  for (int c = 0; c < C1C; c++){
    sum[c] = xls0[c] * alpha0;
    if (two) sum[c] = fmaf(xls1[c], alpha1, sum[c]);
  }
  #pragma unroll
  for (int m = 32; m; m >>= 1){
    #pragma unroll
    for (int c = 0; c < C1C; c++) sum[c] += __shfl_xor(sum[c], m);
  }
  if (lane == 0){
    float* h1p = h1 + ((size_t)t * SCAP + s) * HID + h * C1C;
    #pragma unroll
    for (int c = 0; c < C1C; c++){
      float v = sum[c] + b1[h * C1C + c];
      h1p[c] = v > 0.f ? v : expm1f(v);   // ELU
    }
  }
}

// ---- K5: layer-2 GAT at node 0 only -> series[t]. One wave per t. ----
__global__ __launch_bounds__(64) void k_gat2(const int* __restrict__ ei, const float* __restrict__ Wl2,
                                             const float* __restrict__ attl2_, const float* __restrict__ attr2_,
                                             const float* __restrict__ b2, const int* __restrict__ cnt2,
                                             const int* __restrict__ list2, const int* __restrict__ slot_of,
                                             const float* __restrict__ h1, float* __restrict__ series){
  int t = blockIdx.x; int lane = threadIdx.x;
  int deg = min(cnt2[t], CAP2);
  int tot = deg + 1;
  const int* srcp = ei + (size_t)t * 2 * NE;
  const int* so = slot_of + (size_t)t * NN;
  float attl2 = attl2_[0], attr2 = attr2_[0];
  int sl0 = so[0];
  const float* h1t = h1 + (size_t)t * SCAP * HID;

  float x0 = 0.f;
  for (int k = 0; k < HID; k++) x0 += h1t[(size_t)sl0 * HID + k] * Wl2[k];

  bool act[2]; int eid[2]; float xl2[2];
  #pragma unroll
  for (int ch = 0; ch < 2; ch++){
    int idx = ch * 64 + lane;
    act[ch] = idx < tot;
    eid[ch] = 1 << 29;
    int sl = sl0;
    if (idx < deg){ int e = list2[t * CAP2 + idx]; eid[ch] = e; sl = so[srcp[e]]; }
    float v = 0.f;
    if (act[ch]) for (int k = 0; k < HID; k++) v += h1t[(size_t)sl * HID + k] * Wl2[k];
    xl2[ch] = v;
  }
  float raw[2];
  #pragma unroll
  for (int ch = 0; ch < 2; ch++) raw[ch] = act[ch] ? leaky(attl2 * xl2[ch] + attr2 * x0) : -INFINITY;
  float M = wave_max(fmaxf(raw[0], raw[1]));
  float ex[2];
  #pragma unroll
  for (int ch = 0; ch < 2; ch++) ex[ch] = act[ch] ? expf(raw[ch] - M) : 0.f;
  float S = wave_sum(ex[0] + ex[1]);
  float den = S + 1e-16f;
  float contrib = apply_edit(ex[0] / den, eid[0]) * xl2[0] + apply_edit(ex[1] / den, eid[1]) * xl2[1];
  contrib = wave_sum(contrib);
  if (lane == 0) series[t] = contrib + b2[0];   // 1 head, mean == identity
}

// ---- K7: LSTM — 1024 thr/block, pair-per-row, interleaved halves, streaming loads. ----
// Round-13 post-mortem: TT=8 phase-B tile hit the pre-committed tripwire — WRITE_SIZE 1KB->202MB,
// k_lstm 94->458us. Allocator chose VGPR=64 (had 128 budget) and spilled the 8-acc tile + 8 LDS
// pointers; every AFMA became a scratch RMW. This allocator prices spills ~0 and refuses >~64
// arch VGPRs here. Per pre-commitment: TT=4, minimal live state — no stored pointer array (inline
// h0buf[t0+k] addressing), 4 named float4 accs + 1 weight + transient hv ~= 40 live regs.
// Weight traffic in phase B still drops 4x (8MB -> 2MB/block) ~= -23us of its ~31us.
// Verify: WRITE_SIZE ~0 (jump = tiling permanently dead -> revert to r7 phase B), dur ~72-78us.
// (Round-14: identical resubmit — round-9 bench was an infra failure, no data.)
__global__ __launch_bounds__(1024, 4) void k_lstm(const float* __restrict__ series,
    const float* __restrict__ Wih0, const float* __restrict__ Whh0,
    const float* __restrict__ bih0, const float* __restrict__ bhh0,
    const float* __restrict__ Wih1, const float* __restrict__ Whh1,
    const float* __restrict__ bih1, const float* __restrict__ bhh1,
    const float* __restrict__ Wlin, const float* __restrict__ blin,
    float* __restrict__ out){
  int tid = threadIdx.x;
  int b = blockIdx.x;
  int r  = tid >> 1;        // gate row 0..511
  int hf = tid & 1;         // which interleaved half of the 128-dot this thread owns
  int cls = r >> 7;         // gate class 0:i 1:f 2:g 3:o — g uses tanh, rest sigmoid
  __shared__ __align__(16) float h_lds[LH];
  __shared__ __align__(16) float c_lds[LH];
  __shared__ __align__(16) float gate_lds[G4];
  __shared__ __align__(16) float s_series[NL];
  __shared__ __align__(16) float h0buf[NL][LH];     // 16 KB: layer-0 hidden states
  __shared__ __align__(16) float xp_lds[NL * G4];   // 64 KB: Wih1 @ h0 for all t

  // ---------- phase A: layer-0 recurrence ----------
  {
    const float4* Wr = (const float4*)(Whh0 + (size_t)r * LH);
    const float4* hp = (const float4*)h_lds;
    float wih = Wih0[r];
    float bsum = bih0[r] + bhh0[r];
    if (tid < LH){ h_lds[tid] = 0.f; c_lds[tid] = 0.f; }
    if (tid < NL) s_series[tid] = series[b + tid];
    __syncthreads();
    for (int t = 0; t < NL; t++){
      float a0 = 0.f, a1 = 0.f, a2 = 0.f, a3 = 0.f;
      #pragma unroll
      for (int i = 0; i < 16; i++){
        float4 w = Wr[2 * i + hf];
        float4 hv = hp[2 * i + hf];
        a0 = fmaf(w.x, hv.x, a0); a1 = fmaf(w.y, hv.y, a1);
        a2 = fmaf(w.z, hv.z, a2); a3 = fmaf(w.w, hv.w, a3);
      }
      float half = (a0 + a1) + (a2 + a3);
      float full = half + __shfl_xor(half, 1);
      if (!hf){
        float acc = fmaf(wih, s_series[t], bsum) + full;
        gate_lds[r] = (cls == 2) ? tanhf(acc) : sigmoidf(acc);
      }
      __syncthreads();
      if (tid < LH){
        float c = gate_lds[LH + tid] * c_lds[tid] + gate_lds[tid] * gate_lds[2 * LH + tid];
        float h = gate_lds[3 * LH + tid] * tanhf(c);
        c_lds[tid] = c; h_lds[tid] = h; h0buf[t][tid] = h;
      }
      __syncthreads();
    }
  }

  // ---------- phase B: xp[t][r] = Wih1[r,:] @ h0[t] — weight-register tiling over 4 t's ----------
  {
    const float4* Wr = (const float4*)(Wih1 + (size_t)r * LH);
    const float4* h0p = (const float4*)h0buf;       // [NL][LH/4] flattened: t*32 + idx
    for (int t0 = 0; t0 < NL; t0 += 4){
      float4 c0 = {0.f,0.f,0.f,0.f};
      float4 c1 = {0.f,0.f,0.f,0.f};
      float4 c2 = {0.f,0.f,0.f,0.f};
      float4 c3 = {0.f,0.f,0.f,0.f};
      #pragma unroll
      for (int i = 0; i < 16; i++){
        float4 w = Wr[2 * i + hf];
        int base = t0 * 32 + 2 * i + hf;
        float4 v0 = h0p[base];
        float4 v1 = h0p[base + 32];
        float4 v2 = h0p[base + 64];
        float4 v3 = h0p[base + 96];
        c0.x = fmaf(w.x, v0.x, c0.x); c0.y = fmaf(w.y, v0.y, c0.y);
        c0.z = fmaf(w.z, v0.z, c0.z); c0.w = fmaf(w.w, v0.w, c0.w);
        c1.x = fmaf(w.x, v1.x, c1.x); c1.y = fmaf(w.y, v1.y, c1.y);
        c1.z = fmaf(w.z, v1.z, c1.z); c1.w = fmaf(w.w, v1.w, c1.w);
        c2.x = fmaf(w.x, v2.x, c2.x); c2.y = fmaf(w.y, v2.y, c2.y);
        c2.z = fmaf(w.z, v2.z, c2.z); c2.w = fmaf(w.w, v2.w, c2.w);
        c3.x = fmaf(w.x, v3.x, c3.x); c3.y = fmaf(w.y, v3.y, c3.y);
        c3.z = fmaf(w.z, v3.z, c3.z); c3.w = fmaf(w.w, v3.w, c3.w);
      }
      float h0s = (c0.x + c0.y) + (c0.z + c0.w);
      float h1s = (c1.x + c1.y) + (c1.z + c1.w);
      float h2s = (c2.x + c2.y) + (c2.z + c2.w);
      float h3s = (c3.x + c3.y) + (c3.z + c3.w);
      float f0 = h0s + __shfl_xor(h0s, 1);
      float f1 = h1s + __shfl_xor(h1s, 1);
      float f2 = h2s + __shfl_xor(h2s, 1);
      float f3 = h3s + __shfl_xor(h3s, 1);
      if (!hf){
        xp_lds[(t0 + 0) * G4 + r] = f0;
        xp_lds[(t0 + 1) * G4 + r] = f1;
        xp_lds[(t0 + 2) * G4 + r] = f2;
        xp_lds[(t0 + 3) * G4 + r] = f3;
      }
    }
  }

  // ---------- phase C: layer-1 recurrence ----------
  {
    const float4* Wr = (const float4*)(Whh1 + (size_t)r * LH);
    const float4* hp = (const float4*)h_lds;
    float bsum = bih1[r] + bhh1[r];
    __syncthreads();                      // all waves out of phase B before h/c reinit
    if (tid < LH){ h_lds[tid] = 0.f; c_lds[tid] = 0.f; }
    __syncthreads();
    for (int t = 0; t < NL; t++){
      float a0 = 0.f, a1 = 0.f, a2 = 0.f, a3 = 0.f;
      #pragma unroll
      for (int i = 0; i < 16; i++){
        float4 w = Wr[2 * i + hf];
        float4 hv = hp[2 * i + hf];
        a0 = fmaf(w.x, hv.x, a0); a1 = fmaf(w.y, hv.y, a1);
        a2 = fmaf(w.z, hv.z, a2); a3 = fmaf(w.w, hv.w, a3);
      }
      float half = (a0 + a1) + (a2 + a3);
      float full = half + __shfl_xor(half, 1);
      if (!hf){
        float acc = xp_lds[t * G4 + r] + bsum + full;   // xp: own pair's phase-B write
        gate_lds[r] = (cls == 2) ? tanhf(acc) : sigmoidf(acc);
      }
      __syncthreads();
      if (tid < LH){
        float c = gate_lds[LH + tid] * c_lds[tid] + gate_lds[tid] * gate_lds[2 * LH + tid];
        float h = gate_lds[3 * LH + tid] * tanhf(c);
        c_lds[tid] = c; h_lds[tid] = h;
      }
      __syncthreads();
    }
    if (tid == 0){
      float s2 = blin[0];
      for (int k = 0; k < LH; k++) s2 += Wlin[k] * h_lds[k];
      out[b] = s2;
    }
  }
}

extern "C" void kernel_launch(void* const* d_in, const int* in_sizes, int n_in,
                              void* d_out, int out_size, void* d_ws, size_t ws_size,
                              hipStream_t stream) {
  const float* x     = (const float*)d_in[0];
  const int*   ei    = (const int*)  d_in[1];
  const float* Wl1   = (const float*)d_in[2];
  const float* attl1 = (const float*)d_in[3];
  const float* attr1 = (const float*)d_in[4];
  const float* b1    = (const float*)d_in[5];
  const float* Wl2   = (const float*)d_in[6];
  const float* attl2 = (const float*)d_in[7];
  const float* attr2 = (const float*)d_in[8];
  const float* b2    = (const float*)d_in[9];
  const float* Wih0  = (const float*)d_in[10];
  const float* Whh0  = (const float*)d_in[11];
  const float* bih0  = (const float*)d_in[12];
  const float* bhh0  = (const float*)d_in[13];
  const float* Wih1  = (const float*)d_in[14];
  const float* Whh1  = (const float*)d_in[15];
  const float* bih1  = (const float*)d_in[16];
  const float* bhh1  = (const float*)d_in[17];
  const float* Wlin  = (const float*)d_in[18];
  const float* blin  = (const float*)d_in[19];
  float* out = (float*)d_out;

  char* wsb = (char*)d_ws;
  size_t off = 0;
  auto alloc = [&](size_t bytes)->void*{
    void* p = wsb + off;
    off += (bytes + 255) & ~(size_t)255;
    return p;
  };
  // control region (must be zeroed each launch — ws is poisoned 0xAA)
  int* cnt2  = (int*)alloc(T * 4);
  int* scnt  = (int*)alloc(T * 4);
  int* ecnt1 = (int*)alloc(T * SCAP * 4);
  size_t ctrl_bytes = off;
  int* slot_of = (int*)alloc((size_t)T * NN * 4);       // memset 0xFF -> -1
  int* list2   = (int*)alloc((size_t)T * CAP2 * 4);
  int* Slist   = (int*)alloc((size_t)T * SCAP * 4);
  int* elist1  = (int*)alloc((size_t)T * SCAP * DEGCAP * 4);
  float* h1    = (float*)alloc((size_t)T * SCAP * HID * 4);
  float* series= (float*)alloc(T * 4);

  hipMemsetAsync(d_ws, 0, ctrl_bytes, stream);
  hipMemsetAsync(slot_of, 0xFF, (size_t)T * NN * 4, stream);

  k_scan0<<<T * NE / 4 / 256, 256, 0, stream>>>(ei, cnt2, list2);
  k_build<<<T, 128, 0, stream>>>(ei, cnt2, list2, scnt, Slist, slot_of);
  k_scan1<<<T * NE / 4 / 256, 256, 0, stream>>>(ei, slot_of, ecnt1, elist1);
  k_gat1<<<dim3(SCAP, T, H1H), 64, 0, stream>>>(x, ei, Wl1, attl1, attr1, b1, scnt, Slist, ecnt1, elist1, h1);
  k_gat2<<<T, 64, 0, stream>>>(ei, Wl2, attl2, attr2, b2, cnt2, list2, slot_of, h1, series);
  k_lstm<<<NB, 1024, 0, stream>>>(series, Wih0, Whh0, bih0, bhh0, Wih1, Whh1, bih1, bhh1,
                                  Wlin, blin, out);
}